// Round 4
// baseline (1288.604 us; speedup 1.0000x reference)
//
#include <hip/hip_runtime.h>
#include <hip/hip_fp16.h>
#include <cmath>

#define TOKENS 2048
#define DMODEL 2048
#define DHID   5632
#define NEXP   8
#define RANK   16
#define LALPHA 2.0f

typedef __attribute__((ext_vector_type(4))) float f32x4;
typedef __attribute__((ext_vector_type(8))) short s16x8;
typedef __attribute__((ext_vector_type(4))) short s16x4;
typedef __attribute__((ext_vector_type(8))) _Float16 f16x8;

__device__ __forceinline__ short f2bf(float f){
  unsigned u = __float_as_uint(f);
  u += 0x7fffu + ((u >> 16) & 1u);
  return (short)(u >> 16);
}
__device__ __forceinline__ short f2h(float f){
  return (short)__half_as_ushort(__float2half(f));
}

// ---------- async global->LDS staging of a 128x32 bf16/f16 tile ----------
// LDS tile = 512 slots of 16B, linear. slot L: row r=L>>2, phys chunk p=L&3.
// Logical k-chunk c stored at p=(c+(r>>1))&3 => 2-way-only bank aliasing (free).
struct Stage { const short* s0; const short* s1; short* d0; short* d1; };

__device__ __forceinline__ Stage mk_stage(const short* g, long ld, short* t, int tid){
  Stage st;
  const int L0 = tid,      r0 = L0>>2, c0 = ((L0&3) - (r0>>1)) & 3;
  const int L1 = 256+tid,  r1 = L1>>2, c1 = ((L1&3) - (r1>>1)) & 3;
  st.s0 = g + (long)r0*ld + c0*8;  st.d0 = t + L0*8;
  st.s1 = g + (long)r1*ld + c1*8;  st.d1 = t + L1*8;
  return st;
}
__device__ __forceinline__ void do_stage(const Stage& st, int k0){
  __builtin_amdgcn_global_load_lds((const __attribute__((address_space(1))) void*)(st.s0 + k0),
                                   (__attribute__((address_space(3))) void*)st.d0, 16, 0, 0);
  __builtin_amdgcn_global_load_lds((const __attribute__((address_space(1))) void*)(st.s1 + k0),
                                   (__attribute__((address_space(3))) void*)st.d1, 16, 0, 0);
}
__device__ __forceinline__ s16x8 fragb(const short* t, int row, int quad){
  const int p = (quad + (row>>1)) & 3;
  return *(const s16x8*)(t + (row*4 + p)*8);
}
__device__ __forceinline__ f16x8 fragh(const short* t, int row, int quad){
  const int p = (quad + (row>>1)) & 3;
  return *(const f16x8*)(t + (row*4 + p)*8);
}

// ---------------- K0: cast/gather all GEMM operands ----------------
__global__ void k_cast(const float* __restrict__ x, const float* __restrict__ w_up,
                       const float* __restrict__ w_gate, const float* __restrict__ w_down,
                       const float* __restrict__ upA, const float* __restrict__ gateA,
                       const float* __restrict__ downA, const float* __restrict__ upB,
                       const float* __restrict__ gateB, const float* __restrict__ downB,
                       short* __restrict__ xb, short* __restrict__ wub, short* __restrict__ wgb,
                       short* __restrict__ wdb, short* __restrict__ daA, short* __restrict__ acat,
                       short* __restrict__ upBcat, short* __restrict__ gateBcat, short* __restrict__ wdbcat){
  const long e0 = 4194304, e1 = 15728640, e2 = 27262976, e3 = 38797312;
  const long e4 = 39518208, e5 = 40042496, e6 = 40763392, e7 = 41484288, e8 = 41746432;
  const long i = ((long)blockIdx.x*256 + threadIdx.x) * 4;
  if(i >= e8) return;
  const float* src; short* dst; long l; int fp16 = 0;
  if(i < e0){ src = x; dst = xb; l = i; }
  else if(i < e1){ src = w_up; dst = wub; l = i - e0; }
  else if(i < e2){ src = w_gate; dst = wgb; l = i - e1; }
  else if(i < e3){ src = w_down; dst = wdb; l = i - e2; }
  else if(i < e4){ src = downA; dst = daA; l = i - e3; }   // daA[c][h] == downA flat
  else if(i < e5){ // acat[c][d] = (pj?gateA:upA)[e][r][d], c = e*32+pj*16+r
    l = i - e4;
    const long c = l>>11;
    const long e = c>>5, pj = (c>>4)&1, r = c&15;
    src = (pj ? gateA : upA) + ((e*RANK + r)<<11) + (l&2047) - l;
    dst = acat;
  }
  else if(i < e6){ // upBcat[h][e*16+r] = upB[e][h][r]  (f16)
    l = i - e5;
    const long h = l>>7, c = l&127, e = c>>4, r = c&15;
    src = upB + ((e*DHID + h)*RANK + r) - l;
    dst = upBcat; fp16 = 1;
  }
  else if(i < e7){ // gateBcat
    l = i - e6;
    const long h = l>>7, c = l&127, e = c>>4, r = c&15;
    src = gateB + ((e*DHID + h)*RANK + r) - l;
    dst = gateBcat; fp16 = 1;
  }
  else { // wdbcat[d][e*16+r] = downB[e][d][r]  (f16)
    l = i - e7;
    const long d = l>>7, c = l&127, e = c>>4, r = c&15;
    src = downB + ((e*DMODEL + d)*RANK + r) - l;
    dst = wdbcat; fp16 = 1;
  }
  const float4 v = *(const float4*)(src + l);
  s16x4 o;
  if(fp16){ o[0]=f2h(v.x); o[1]=f2h(v.y); o[2]=f2h(v.z); o[3]=f2h(v.w); }
  else    { o[0]=f2bf(v.x); o[1]=f2bf(v.y); o[2]=f2bf(v.z); o[3]=f2bf(v.w); }
  *(s16x4*)(dst + l) = o;
}

// ---------------- K1: router logits (fp32, one wave per token) + top-2 ----------------
__global__ void k_router(const float* __restrict__ x, const float* __restrict__ gw,
                         int* __restrict__ sel, float* __restrict__ topv){
  const int t = blockIdx.x*4 + (threadIdx.x>>6);
  const int lane = threadIdx.x & 63;
  const float* xr = x + (long)t * DMODEL;
  float acc[NEXP];
  #pragma unroll
  for(int e=0;e<NEXP;e++) acc[e]=0.f;
  #pragma unroll
  for(int it=0; it<8; it++){
    const int d = it*256 + lane*4;
    const float4 xv = *(const float4*)(xr + d);
    #pragma unroll
    for(int e=0;e<NEXP;e++){
      const float4 wv = *(const float4*)(gw + e*DMODEL + d);
      acc[e] += xv.x*wv.x + xv.y*wv.y + xv.z*wv.z + xv.w*wv.w;
    }
  }
  #pragma unroll
  for(int e=0;e<NEXP;e++){
    #pragma unroll
    for(int off=32; off; off>>=1) acc[e] += __shfl_down(acc[e], off, 64);
  }
  if(lane==0){
    int i0=0;
    #pragma unroll
    for(int e=1;e<NEXP;e++) if(acc[e]>acc[i0]) i0=e;
    int i1=-1;
    #pragma unroll
    for(int e=0;e<NEXP;e++){ if(e==i0) continue; if(i1<0 || acc[e]>acc[i1]) i1=e; }
    sel[t*2+0]=i0; sel[t*2+1]=i1;
    topv[t*2+0]=acc[i0]; topv[t*2+1]=acc[i1];
  }
}

// ---------------- K2: softmax over the SEQUENCE axis (faithful) ----------------
__global__ void k_softmax(const float* __restrict__ topv, float* __restrict__ cw){
  const int b = blockIdx.x >> 1, k = blockIdx.x & 1;
  const int base = b*1024;
  __shared__ float red[256];
  float v[4];
  float mx = -1e30f;
  #pragma unroll
  for(int i=0;i<4;i++){
    int s = threadIdx.x + i*256;
    v[i] = topv[(base+s)*2 + k];
    mx = fmaxf(mx, v[i]);
  }
  red[threadIdx.x]=mx; __syncthreads();
  for(int o=128;o;o>>=1){ if(threadIdx.x<o) red[threadIdx.x]=fmaxf(red[threadIdx.x],red[threadIdx.x+o]); __syncthreads(); }
  mx = red[0]; __syncthreads();
  float sum=0.f;
  #pragma unroll
  for(int i=0;i<4;i++){ v[i]=__expf(v[i]-mx); sum+=v[i]; }
  red[threadIdx.x]=sum; __syncthreads();
  for(int o=128;o;o>>=1){ if(threadIdx.x<o) red[threadIdx.x]+=red[threadIdx.x+o]; __syncthreads(); }
  const float inv = 1.f/red[0];
  #pragma unroll
  for(int i=0;i<4;i++){
    int s = threadIdx.x + i*256;
    cw[(base+s)*2+k] = v[i]*inv;
  }
}

// ---------------- K3: Rall = X @ Acat^T (dense, N=256) ----------------
__global__ __launch_bounds__(256,3) void k_rank(
    const short* __restrict__ xb, const short* __restrict__ acat, float* __restrict__ Rall){
  __shared__ __align__(16) short At[4096];
  __shared__ __align__(16) short Bt[4096];
  const int c0 = blockIdx.x*128, t0 = blockIdx.y*128;
  const int tid = threadIdx.x, lane = tid&63, wave = tid>>6;
  const int wm=(wave>>1)*64, wn=(wave&1)*64, fr=lane&15, quad=lane>>4;
  f32x4 acc[4][4];
  #pragma unroll
  for(int i=0;i<4;i++)
    #pragma unroll
    for(int j=0;j<4;j++) acc[i][j]=(f32x4){0.f,0.f,0.f,0.f};
  const Stage sA = mk_stage(xb + (long)t0*DMODEL, DMODEL, At, tid);
  const Stage sB = mk_stage(acat + (long)c0*DMODEL, DMODEL, Bt, tid);
  for(int k0=0; k0<DMODEL; k0+=32){
    do_stage(sA, k0); do_stage(sB, k0);
    __syncthreads();
    s16x8 af[4];
    #pragma unroll
    for(int i=0;i<4;i++) af[i] = fragb(At, wm + i*16 + fr, quad);
    #pragma unroll
    for(int j=0;j<4;j++){
      const s16x8 bf = fragb(Bt, wn + j*16 + fr, quad);
      #pragma unroll
      for(int i=0;i<4;i++)
        acc[i][j] = __builtin_amdgcn_mfma_f32_16x16x32_bf16(af[i], bf, acc[i][j], 0,0,0);
    }
    __syncthreads();
  }
  #pragma unroll
  for(int i=0;i<4;i++)
    #pragma unroll
    for(int j=0;j<4;j++){
      const int rbase = wm + i*16 + quad*4, col = wn + j*16 + fr;
      #pragma unroll
      for(int reg=0;reg<4;reg++)
        Rall[(long)(t0+rbase+reg)*256 + c0 + col] = acc[i][j][reg];
    }
}

// ---------------- K3b: Rsel[k][t][e*16+r] = (e==sel_k) ? alpha*Rall : 0  (f16) ----------------
__global__ void k_rsel(const float* __restrict__ Rall, const int* __restrict__ sel,
                       short* __restrict__ RselU, short* __restrict__ RselG){
  const int idx = blockIdx.x*256 + threadIdx.x;      // [2][TOKENS][128]
  const int c = idx & 127, t = (idx>>7) & (TOKENS-1), k = idx>>18;
  const int e = c>>4, r = c&15;
  const int s = sel[t*2+k];
  const int m = (e==s);
  RselU[idx] = f2h(m ? LALPHA*Rall[(long)t*256 + e*32 + r]      : 0.f);
  RselG[idx] = f2h(m ? LALPHA*Rall[(long)t*256 + e*32 + 16 + r] : 0.f);
}

// ---------------- K4: base up/gate GEMM + LoRA via MFMA -> ch0, ch1, chsum (bf16) ----------------
__global__ __launch_bounds__(256,3) void k_main(
    const short* __restrict__ xb, const short* __restrict__ wub, const short* __restrict__ wgb,
    const short* __restrict__ RselU, const short* __restrict__ RselG,
    const short* __restrict__ upBcat, const short* __restrict__ gateBcat,
    const float* __restrict__ cw, unsigned short* __restrict__ ch, unsigned short* __restrict__ chsum){
  __shared__ __align__(16) short At[4096];
  __shared__ __align__(16) short Ut[4096];
  __shared__ __align__(16) short Gt[4096];
  __shared__ float cwv[128][2];
  const int h0 = blockIdx.x*128, t0 = blockIdx.y*128;
  const int tid = threadIdx.x, lane = tid&63, wave = tid>>6;
  const int wm=(wave>>1)*64, wn=(wave&1)*64, fr=lane&15, quad=lane>>4;
  if(tid < 256){ const int tl = tid>>1, k = tid&1; cwv[tl][k] = cw[(t0+tl)*2 + k]; }
  f32x4 au[4][4], ag[4][4], lu0[4][4], lg0[4][4], lu1[4][4], lg1[4][4];
  #pragma unroll
  for(int i=0;i<4;i++)
    #pragma unroll
    for(int j=0;j<4;j++){
      au[i][j]=(f32x4){0.f,0.f,0.f,0.f}; ag[i][j]=au[i][j];
      lu0[i][j]=au[i][j]; lg0[i][j]=au[i][j]; lu1[i][j]=au[i][j]; lg1[i][j]=au[i][j];
    }
  // ---- base GEMMs: au/ag over K=DMODEL ----
  {
    const Stage sA = mk_stage(xb + (long)t0*DMODEL, DMODEL, At, tid);
    const Stage sU = mk_stage(wub + (long)h0*DMODEL, DMODEL, Ut, tid);
    const Stage sG = mk_stage(wgb + (long)h0*DMODEL, DMODEL, Gt, tid);
    for(int k0=0; k0<DMODEL; k0+=32){
      do_stage(sA, k0); do_stage(sU, k0); do_stage(sG, k0);
      __syncthreads();
      s16x8 af[4];
      #pragma unroll
      for(int i=0;i<4;i++) af[i] = fragb(At, wm + i*16 + fr, quad);
      #pragma unroll
      for(int j=0;j<4;j++){
        const s16x8 bu = fragb(Ut, wn + j*16 + fr, quad);
        const s16x8 bg = fragb(Gt, wn + j*16 + fr, quad);
        #pragma unroll
        for(int i=0;i<4;i++){
          au[i][j] = __builtin_amdgcn_mfma_f32_16x16x32_bf16(af[i], bu, au[i][j], 0,0,0);
          ag[i][j] = __builtin_amdgcn_mfma_f32_16x16x32_bf16(af[i], bg, ag[i][j], 0,0,0);
        }
      }
      __syncthreads();
    }
  }
  // ---- LoRA up: lu0/lu1 over K=128 (f16); B tile (upBcat) shared by both slots ----
  {
    const Stage sB  = mk_stage(upBcat + (long)h0*128, 128, Ut, tid);
    const Stage sR0 = mk_stage(RselU + (long)t0*128, 128, At, tid);
    const Stage sR1 = mk_stage(RselU + ((long)TOKENS + t0)*128, 128, Gt, tid);
    for(int k0=0; k0<128; k0+=32){
      do_stage(sB, k0); do_stage(sR0, k0); do_stage(sR1, k0);
      __syncthreads();
      f16x8 a0[4], a1[4];
      #pragma unroll
      for(int i=0;i<4;i++){ a0[i] = fragh(At, wm + i*16 + fr, quad); a1[i] = fragh(Gt, wm + i*16 + fr, quad); }
      #pragma unroll
      for(int j=0;j<4;j++){
        const f16x8 bf = fragh(Ut, wn + j*16 + fr, quad);
        #pragma unroll
        for(int i=0;i<4;i++){
          lu0[i][j] = __builtin_amdgcn_mfma_f32_16x16x32_f16(a0[i], bf, lu0[i][j], 0,0,0);
          lu1[i][j] = __builtin_amdgcn_mfma_f32_16x16x32_f16(a1[i], bf, lu1[i][j], 0,0,0);
        }
      }
      __syncthreads();
    }
  }
  // ---- LoRA gate: lg0/lg1 over K=128 (f16) ----
  {
    const Stage sB  = mk_stage(gateBcat + (long)h0*128, 128, Ut, tid);
    const Stage sR0 = mk_stage(RselG + (long)t0*128, 128, At, tid);
    const Stage sR1 = mk_stage(RselG + ((long)TOKENS + t0)*128, 128, Gt, tid);
    for(int k0=0; k0<128; k0+=32){
      do_stage(sB, k0); do_stage(sR0, k0); do_stage(sR1, k0);
      __syncthreads();
      f16x8 a0[4], a1[4];
      #pragma unroll
      for(int i=0;i<4;i++){ a0[i] = fragh(At, wm + i*16 + fr, quad); a1[i] = fragh(Gt, wm + i*16 + fr, quad); }
      #pragma unroll
      for(int j=0;j<4;j++){
        const f16x8 bf = fragh(Ut, wn + j*16 + fr, quad);
        #pragma unroll
        for(int i=0;i<4;i++){
          lg0[i][j] = __builtin_amdgcn_mfma_f32_16x16x32_f16(a0[i], bf, lg0[i][j], 0,0,0);
          lg1[i][j] = __builtin_amdgcn_mfma_f32_16x16x32_f16(a1[i], bf, lg1[i][j], 0,0,0);
        }
      }
      __syncthreads();
    }
  }
  // ---- branch-free epilogue ----
  #pragma unroll
  for(int i=0;i<4;i++){
    #pragma unroll
    for(int reg=0;reg<4;reg++){
      const int tl = wm + i*16 + quad*4 + reg;
      const float c0 = cwv[tl][0], c1 = cwv[tl][1];
      unsigned short* r0 = ch + ((long)(t0+tl))*DHID + h0;
      unsigned short* r1 = ch + ((long)TOKENS + t0+tl)*DHID + h0;
      unsigned short* rs = chsum + ((long)(t0+tl))*DHID + h0;
      #pragma unroll
      for(int j=0;j<4;j++){
        const int hl = wn + j*16 + fr;
        const float u0 = au[i][j][reg] + lu0[i][j][reg];
        const float g0 = ag[i][j][reg] + lg0[i][j][reg];
        const float h0v = (u0 / (1.f + __expf(-u0))) * g0;
        const float u1 = au[i][j][reg] + lu1[i][j][reg];
        const float g1 = ag[i][j][reg] + lg1[i][j][reg];
        const float h1v = (u1 / (1.f + __expf(-u1))) * g1;
        const float v0 = c0*h0v, v1 = c1*h1v;
        r0[hl] = (unsigned short)f2bf(v0);
        r1[hl] = (unsigned short)f2bf(v1);
        rs[hl] = (unsigned short)f2bf(v0+v1);
      }
    }
  }
}

// ---------------- K5: RD[t][k][c] = ch_k @ daA^T (ksplit=16, atomics) ----------------
__global__ __launch_bounds__(256,4) void k_rd(
    const unsigned short* __restrict__ ch, const short* __restrict__ daA,
    float* __restrict__ RD){
  __shared__ __align__(16) short At[4096];
  __shared__ __align__(16) short Bt[4096];
  const int slot = blockIdx.x>>4, ks = blockIdx.x&15;
  const int t0 = blockIdx.y*128;
  const int tid = threadIdx.x, lane = tid&63, wave = tid>>6;
  const int wm=(wave>>1)*64, wn=(wave&1)*64, fr=lane&15, quad=lane>>4;
  f32x4 acc[4][4];
  #pragma unroll
  for(int i=0;i<4;i++)
    #pragma unroll
    for(int j=0;j<4;j++) acc[i][j]=(f32x4){0.f,0.f,0.f,0.f};
  const Stage sA = mk_stage((const short*)ch + ((long)slot*TOKENS + t0)*DHID, DHID, At, tid);
  const Stage sB = mk_stage(daA, DHID, Bt, tid);
  const int kbeg = ks*352;
  for(int kk=0; kk<352; kk+=32){
    do_stage(sA, kbeg+kk); do_stage(sB, kbeg+kk);
    __syncthreads();
    s16x8 af[4];
    #pragma unroll
    for(int i=0;i<4;i++) af[i] = fragb(At, wm + i*16 + fr, quad);
    #pragma unroll
    for(int j=0;j<4;j++){
      const s16x8 bf = fragb(Bt, wn + j*16 + fr, quad);
      #pragma unroll
      for(int i=0;i<4;i++)
        acc[i][j] = __builtin_amdgcn_mfma_f32_16x16x32_bf16(af[i], bf, acc[i][j], 0,0,0);
    }
    __syncthreads();
  }
  #pragma unroll
  for(int i=0;i<4;i++)
    #pragma unroll
    for(int j=0;j<4;j++){
      const int rbase = wm + i*16 + quad*4, col = wn + j*16 + fr;
      #pragma unroll
      for(int reg=0;reg<4;reg++)
        atomicAdd(&RD[((long)(t0+rbase+reg)*2 + slot)*128 + col], acc[i][j][reg]);
    }
}

// ---------------- K5b: RDhat[t][c] (f16) = alpha * RD at selected expert blocks ----------------
__global__ void k_scatter(const float* __restrict__ RD, const int* __restrict__ sel,
                          __half* __restrict__ RDhat){
  const int idx = blockIdx.x*256 + threadIdx.x;   // over T*128
  const int t = idx>>7, c = idx&127, e = c>>4;
  const int s0 = sel[t*2], s1 = sel[t*2+1];
  float v = 0.f;
  if(e == s0) v = LALPHA * RD[((long)t*2+0)*128 + c];
  else if(e == s1) v = LALPHA * RD[((long)t*2+1)*128 + c];
  RDhat[idx] = __float2half(v);
}

// ---------------- K6: out += chsum @ wdb^T (split-K=2) + RDhat @ wdbcat^T ----------------
__global__ __launch_bounds__(256,4) void k_down(
    const unsigned short* __restrict__ chsum, const short* __restrict__ wdb,
    const short* __restrict__ RDhat, const short* __restrict__ wdbcat,
    float* __restrict__ out){
  __shared__ __align__(16) short At[4096];
  __shared__ __align__(16) short Bt[4096];
  const int d0 = blockIdx.x*128, t0 = blockIdx.y*128, ks = blockIdx.z;
  const int tid = threadIdx.x, lane = tid&63, wave = tid>>6;
  const int wm=(wave>>1)*64, wn=(wave&1)*64, fr=lane&15, quad=lane>>4;
  f32x4 acc[4][4];
  #pragma unroll
  for(int i=0;i<4;i++)
    #pragma unroll
    for(int j=0;j<4;j++) acc[i][j]=(f32x4){0.f,0.f,0.f,0.f};
  const Stage sA = mk_stage((const short*)chsum + (long)t0*DHID, DHID, At, tid);
  const Stage sB = mk_stage(wdb + (long)d0*DHID, DHID, Bt, tid);
  const int kbeg = ks*2816;
  for(int kk=0; kk<2816; kk+=32){
    do_stage(sA, kbeg+kk); do_stage(sB, kbeg+kk);
    __syncthreads();
    s16x8 af[4];
    #pragma unroll
    for(int i=0;i<4;i++) af[i] = fragb(At, wm + i*16 + fr, quad);
    #pragma unroll
    for(int j=0;j<4;j++){
      const s16x8 bf = fragb(Bt, wn + j*16 + fr, quad);
      #pragma unroll
      for(int i=0;i<4;i++)
        acc[i][j] = __builtin_amdgcn_mfma_f32_16x16x32_bf16(af[i], bf, acc[i][j], 0,0,0);
    }
    __syncthreads();
  }
  if(ks == 0){
    // LoRA-down phase: K=128 over RDhat (f16) @ wdbcat (f16)
    const Stage sAh = mk_stage(RDhat + (long)t0*128, 128, At, tid);
    const Stage sBh = mk_stage(wdbcat + (long)d0*128, 128, Bt, tid);
    for(int k0=0; k0<128; k0+=32){
      do_stage(sAh, k0); do_stage(sBh, k0);
      __syncthreads();
      f16x8 af[4];
      #pragma unroll
      for(int i=0;i<4;i++) af[i] = fragh(At, wm + i*16 + fr, quad);
      #pragma unroll
      for(int j=0;j<4;j++){
        const f16x8 bf = fragh(Bt, wn + j*16 + fr, quad);
        #pragma unroll
        for(int i=0;i<4;i++)
          acc[i][j] = __builtin_amdgcn_mfma_f32_16x16x32_f16(af[i], bf, acc[i][j], 0,0,0);
      }
      __syncthreads();
    }
  }
  #pragma unroll
  for(int i=0;i<4;i++)
    #pragma unroll
    for(int j=0;j<4;j++){
      const int rbase = wm + i*16 + quad*4, col = wn + j*16 + fr;
      #pragma unroll
      for(int reg=0;reg<4;reg++)
        atomicAdd(&out[(long)(t0+rbase+reg)*DMODEL + d0 + col], acc[i][j][reg]);
    }
}

extern "C" void kernel_launch(void* const* d_in, const int* in_sizes, int n_in,
                              void* d_out, int out_size, void* d_ws, size_t ws_size,
                              hipStream_t stream){
  (void)in_sizes; (void)n_in; (void)out_size; (void)ws_size;
  const float* x      = (const float*)d_in[0];
  const float* gate_w = (const float*)d_in[1];
  const float* w_up   = (const float*)d_in[2];
  const float* w_gate = (const float*)d_in[3];
  const float* w_down = (const float*)d_in[4];
  const float* up_A   = (const float*)d_in[5];
  const float* up_B   = (const float*)d_in[6];
  const float* gate_A = (const float*)d_in[7];
  const float* gate_B = (const float*)d_in[8];
  const float* down_A = (const float*)d_in[9];
  const float* down_B = (const float*)d_in[10];
  float* out = (float*)d_out;

  char* ws = (char*)d_ws;
  size_t off = 0;
  auto alloc = [&](size_t bytes){ void* p = ws + off; off += (bytes + 255) & ~(size_t)255; return p; };
  short* xb       = (short*)alloc((size_t)TOKENS*DMODEL*2);
  short* wub      = (short*)alloc((size_t)DHID*DMODEL*2);
  short* wgb      = (short*)alloc((size_t)DHID*DMODEL*2);
  short* wdb      = (short*)alloc((size_t)DMODEL*DHID*2);
  short* daA      = (short*)alloc((size_t)128*DHID*2);
  short* acat     = (short*)alloc((size_t)256*DMODEL*2);
  short* upBcat   = (short*)alloc((size_t)DHID*128*2);
  short* gateBcat = (short*)alloc((size_t)DHID*128*2);
  short* wdbcat   = (short*)alloc((size_t)DMODEL*128*2);
  unsigned short* ch    = (unsigned short*)alloc((size_t)2*TOKENS*DHID*2);
  unsigned short* chsum = (unsigned short*)alloc((size_t)TOKENS*DHID*2);
  float* Rall   = (float*)alloc((size_t)TOKENS*256*4);
  short* RselU  = (short*)alloc((size_t)2*TOKENS*128*2);
  short* RselG  = (short*)alloc((size_t)2*TOKENS*128*2);
  float* RD     = (float*)alloc((size_t)TOKENS*2*128*4);
  __half* RDhat = (__half*)alloc((size_t)TOKENS*128*2);
  int*   sel    = (int*)alloc((size_t)TOKENS*2*4);
  float* topv   = (float*)alloc((size_t)TOKENS*2*4);
  float* cw     = (float*)alloc((size_t)TOKENS*2*4);

  (void)hipMemsetAsync(RD, 0, (size_t)TOKENS*2*128*4, stream);
  (void)hipMemsetAsync(out, 0, (size_t)TOKENS*DMODEL*4, stream);
  k_cast<<<40768, 256, 0, stream>>>(x, w_up, w_gate, w_down, up_A, gate_A, down_A,
                                    up_B, gate_B, down_B,
                                    xb, wub, wgb, wdb, daA, acat, upBcat, gateBcat, wdbcat);
  k_router<<<512, 256, 0, stream>>>(x, gate_w, sel, topv);
  k_softmax<<<4, 256, 0, stream>>>(topv, cw);
  k_rank<<<dim3(2,16), 256, 0, stream>>>(xb, acat, Rall);
  k_rsel<<<2048, 256, 0, stream>>>(Rall, sel, RselU, RselG);
  k_main<<<dim3(44,16), 256, 0, stream>>>(xb, wub, wgb, RselU, RselG, upBcat, gateBcat, cw, ch, chsum);
  k_rd<<<dim3(32,16), 256, 0, stream>>>(ch, daA, RD);
  k_scatter<<<1024, 256, 0, stream>>>(RD, sel, RDhat);
  k_down<<<dim3(16,16,2), 256, 0, stream>>>(chsum, wdb, (const short*)RDhat, wdbcat, out);
}

// Round 5
// 581.942 us; speedup vs baseline: 2.2143x; 2.2143x over previous
//
#include <hip/hip_runtime.h>
#include <hip/hip_fp16.h>
#include <cmath>

#define TOKENS 2048
#define DMODEL 2048
#define DHID   5632
#define NEXP   8
#define RANK   16
#define LALPHA 2.0f

typedef __attribute__((ext_vector_type(4))) float f32x4;
typedef __attribute__((ext_vector_type(8))) short s16x8;
typedef __attribute__((ext_vector_type(4))) short s16x4;
typedef __attribute__((ext_vector_type(8))) _Float16 f16x8;

__device__ __forceinline__ short f2bf(float f){
  unsigned u = __float_as_uint(f);
  u += 0x7fffu + ((u >> 16) & 1u);
  return (short)(u >> 16);
}
__device__ __forceinline__ short f2h(float f){
  return (short)__half_as_ushort(__float2half(f));
}

// ---------- async global->LDS staging of a 128x32 bf16/f16 tile ----------
// LDS tile = 512 slots of 16B, linear. slot L: row r=L>>2, phys chunk p=L&3.
// Logical k-chunk c stored at p=(c+(r>>1))&3 => 2-way-only bank aliasing (free).
struct Stage { const short* s0; const short* s1; short* d0; short* d1; };

__device__ __forceinline__ Stage mk_stage(const short* g, long ld, short* t, int tid){
  Stage st;
  const int L0 = tid,      r0 = L0>>2, c0 = ((L0&3) - (r0>>1)) & 3;
  const int L1 = 256+tid,  r1 = L1>>2, c1 = ((L1&3) - (r1>>1)) & 3;
  st.s0 = g + (long)r0*ld + c0*8;  st.d0 = t + L0*8;
  st.s1 = g + (long)r1*ld + c1*8;  st.d1 = t + L1*8;
  return st;
}
__device__ __forceinline__ void do_stage(const Stage& st, int k0){
  __builtin_amdgcn_global_load_lds((const __attribute__((address_space(1))) void*)(st.s0 + k0),
                                   (__attribute__((address_space(3))) void*)st.d0, 16, 0, 0);
  __builtin_amdgcn_global_load_lds((const __attribute__((address_space(1))) void*)(st.s1 + k0),
                                   (__attribute__((address_space(3))) void*)st.d1, 16, 0, 0);
}
__device__ __forceinline__ s16x8 fragb(const short* t, int row, int quad){
  const int p = (quad + (row>>1)) & 3;
  return *(const s16x8*)(t + (row*4 + p)*8);
}
__device__ __forceinline__ f16x8 fragh(const short* t, int row, int quad){
  const int p = (quad + (row>>1)) & 3;
  return *(const f16x8*)(t + (row*4 + p)*8);
}

// ---------------- K0: cast/gather all GEMM operands ----------------
__global__ void k_cast(const float* __restrict__ x, const float* __restrict__ w_up,
                       const float* __restrict__ w_gate, const float* __restrict__ w_down,
                       const float* __restrict__ upA, const float* __restrict__ gateA,
                       const float* __restrict__ downA, const float* __restrict__ upB,
                       const float* __restrict__ gateB, const float* __restrict__ downB,
                       short* __restrict__ xb, short* __restrict__ wub, short* __restrict__ wgb,
                       short* __restrict__ wdb, short* __restrict__ daA, short* __restrict__ acat,
                       short* __restrict__ upBcat, short* __restrict__ gateBcat, short* __restrict__ wdbcat){
  const long e0 = 4194304, e1 = 15728640, e2 = 27262976, e3 = 38797312;
  const long e4 = 39518208, e5 = 40042496, e6 = 40763392, e7 = 41484288, e8 = 41746432;
  const long i = ((long)blockIdx.x*256 + threadIdx.x) * 4;
  if(i >= e8) return;
  const float* src; short* dst; long l; int fp16 = 0;
  if(i < e0){ src = x; dst = xb; l = i; }
  else if(i < e1){ src = w_up; dst = wub; l = i - e0; }
  else if(i < e2){ src = w_gate; dst = wgb; l = i - e1; }
  else if(i < e3){ src = w_down; dst = wdb; l = i - e2; }
  else if(i < e4){ src = downA; dst = daA; l = i - e3; }   // daA[c][h] == downA flat
  else if(i < e5){ // acat[c][d] = (pj?gateA:upA)[e][r][d], c = e*32+pj*16+r
    l = i - e4;
    const long c = l>>11;
    const long e = c>>5, pj = (c>>4)&1, r = c&15;
    src = (pj ? gateA : upA) + ((e*RANK + r)<<11) + (l&2047) - l;
    dst = acat;
  }
  else if(i < e6){ // upBcat[h][e*16+r] = upB[e][h][r]  (f16)
    l = i - e5;
    const long h = l>>7, c = l&127, e = c>>4, r = c&15;
    src = upB + ((e*DHID + h)*RANK + r) - l;
    dst = upBcat; fp16 = 1;
  }
  else if(i < e7){ // gateBcat
    l = i - e6;
    const long h = l>>7, c = l&127, e = c>>4, r = c&15;
    src = gateB + ((e*DHID + h)*RANK + r) - l;
    dst = gateBcat; fp16 = 1;
  }
  else { // wdbcat[d][e*16+r] = downB[e][d][r]  (f16)
    l = i - e7;
    const long d = l>>7, c = l&127, e = c>>4, r = c&15;
    src = downB + ((e*DMODEL + d)*RANK + r) - l;
    dst = wdbcat; fp16 = 1;
  }
  const float4 v = *(const float4*)(src + l);
  s16x4 o;
  if(fp16){ o[0]=f2h(v.x); o[1]=f2h(v.y); o[2]=f2h(v.z); o[3]=f2h(v.w); }
  else    { o[0]=f2bf(v.x); o[1]=f2bf(v.y); o[2]=f2bf(v.z); o[3]=f2bf(v.w); }
  *(s16x4*)(dst + l) = o;
}

// ---------------- K1: router logits (fp32, one wave per token) + top-2 ----------------
__global__ void k_router(const float* __restrict__ x, const float* __restrict__ gw,
                         int* __restrict__ sel, float* __restrict__ topv){
  const int t = blockIdx.x*4 + (threadIdx.x>>6);
  const int lane = threadIdx.x & 63;
  const float* xr = x + (long)t * DMODEL;
  float acc[NEXP];
  #pragma unroll
  for(int e=0;e<NEXP;e++) acc[e]=0.f;
  #pragma unroll
  for(int it=0; it<8; it++){
    const int d = it*256 + lane*4;
    const float4 xv = *(const float4*)(xr + d);
    #pragma unroll
    for(int e=0;e<NEXP;e++){
      const float4 wv = *(const float4*)(gw + e*DMODEL + d);
      acc[e] += xv.x*wv.x + xv.y*wv.y + xv.z*wv.z + xv.w*wv.w;
    }
  }
  #pragma unroll
  for(int e=0;e<NEXP;e++){
    #pragma unroll
    for(int off=32; off; off>>=1) acc[e] += __shfl_down(acc[e], off, 64);
  }
  if(lane==0){
    int i0=0;
    #pragma unroll
    for(int e=1;e<NEXP;e++) if(acc[e]>acc[i0]) i0=e;
    int i1=-1;
    #pragma unroll
    for(int e=0;e<NEXP;e++){ if(e==i0) continue; if(i1<0 || acc[e]>acc[i1]) i1=e; }
    sel[t*2+0]=i0; sel[t*2+1]=i1;
    topv[t*2+0]=acc[i0]; topv[t*2+1]=acc[i1];
  }
}

// ---------------- K2: softmax over the SEQUENCE axis (faithful) ----------------
__global__ void k_softmax(const float* __restrict__ topv, float* __restrict__ cw){
  const int b = blockIdx.x >> 1, k = blockIdx.x & 1;
  const int base = b*1024;
  __shared__ float red[256];
  float v[4];
  float mx = -1e30f;
  #pragma unroll
  for(int i=0;i<4;i++){
    int s = threadIdx.x + i*256;
    v[i] = topv[(base+s)*2 + k];
    mx = fmaxf(mx, v[i]);
  }
  red[threadIdx.x]=mx; __syncthreads();
  for(int o=128;o;o>>=1){ if(threadIdx.x<o) red[threadIdx.x]=fmaxf(red[threadIdx.x],red[threadIdx.x+o]); __syncthreads(); }
  mx = red[0]; __syncthreads();
  float sum=0.f;
  #pragma unroll
  for(int i=0;i<4;i++){ v[i]=__expf(v[i]-mx); sum+=v[i]; }
  red[threadIdx.x]=sum; __syncthreads();
  for(int o=128;o;o>>=1){ if(threadIdx.x<o) red[threadIdx.x]+=red[threadIdx.x+o]; __syncthreads(); }
  const float inv = 1.f/red[0];
  #pragma unroll
  for(int i=0;i<4;i++){
    int s = threadIdx.x + i*256;
    cw[(base+s)*2+k] = v[i]*inv;
  }
}

// ---------------- K3: Rall = X @ Acat^T (dense, N=256) ----------------
__global__ __launch_bounds__(256,3) void k_rank(
    const short* __restrict__ xb, const short* __restrict__ acat, float* __restrict__ Rall){
  __shared__ __align__(16) short At[4096];
  __shared__ __align__(16) short Bt[4096];
  const int c0 = blockIdx.x*128, t0 = blockIdx.y*128;
  const int tid = threadIdx.x, lane = tid&63, wave = tid>>6;
  const int wm=(wave>>1)*64, wn=(wave&1)*64, fr=lane&15, quad=lane>>4;
  f32x4 acc[4][4];
  #pragma unroll
  for(int i=0;i<4;i++)
    #pragma unroll
    for(int j=0;j<4;j++) acc[i][j]=(f32x4){0.f,0.f,0.f,0.f};
  const Stage sA = mk_stage(xb + (long)t0*DMODEL, DMODEL, At, tid);
  const Stage sB = mk_stage(acat + (long)c0*DMODEL, DMODEL, Bt, tid);
  for(int k0=0; k0<DMODEL; k0+=32){
    do_stage(sA, k0); do_stage(sB, k0);
    __syncthreads();
    s16x8 af[4];
    #pragma unroll
    for(int i=0;i<4;i++) af[i] = fragb(At, wm + i*16 + fr, quad);
    #pragma unroll
    for(int j=0;j<4;j++){
      const s16x8 bf = fragb(Bt, wn + j*16 + fr, quad);
      #pragma unroll
      for(int i=0;i<4;i++)
        acc[i][j] = __builtin_amdgcn_mfma_f32_16x16x32_bf16(af[i], bf, acc[i][j], 0,0,0);
    }
    __syncthreads();
  }
  #pragma unroll
  for(int i=0;i<4;i++)
    #pragma unroll
    for(int j=0;j<4;j++){
      const int rbase = wm + i*16 + quad*4, col = wn + j*16 + fr;
      #pragma unroll
      for(int reg=0;reg<4;reg++)
        Rall[(long)(t0+rbase+reg)*256 + c0 + col] = acc[i][j][reg];
    }
}

// ---------------- K3b: Rsel[k][t][e*16+r] = (e==sel_k) ? alpha*Rall : 0  (f16) ----------------
__global__ void k_rsel(const float* __restrict__ Rall, const int* __restrict__ sel,
                       short* __restrict__ RselU, short* __restrict__ RselG){
  const int idx = blockIdx.x*256 + threadIdx.x;      // [2][TOKENS][128]
  const int c = idx & 127, t = (idx>>7) & (TOKENS-1), k = idx>>18;
  const int e = c>>4, r = c&15;
  const int s = sel[t*2+k];
  const int m = (e==s);
  RselU[idx] = f2h(m ? LALPHA*Rall[(long)t*256 + e*32 + r]      : 0.f);
  RselG[idx] = f2h(m ? LALPHA*Rall[(long)t*256 + e*32 + 16 + r] : 0.f);
}

// ---------------- K3c: LU/LG[k][t][h] = Rsel_k @ Bcat^T  (f16, K=128, 2 accs only) ----------------
__global__ __launch_bounds__(256,2) void k_lora(
    const short* __restrict__ RselU, const short* __restrict__ RselG,
    const short* __restrict__ upBcat, const short* __restrict__ gateBcat,
    __half* __restrict__ LU, __half* __restrict__ LG){
  __shared__ __align__(16) short At[4096];   // Rsel slot0 tile
  __shared__ __align__(16) short Gt[4096];   // Rsel slot1 tile
  __shared__ __align__(16) short Bt[4096];   // Bcat tile
  const int h0 = blockIdx.x*128, t0 = blockIdx.y*128;
  const short* Rsel = blockIdx.z ? RselG : RselU;
  const short* Bcat = blockIdx.z ? gateBcat : upBcat;
  __half* Lout      = blockIdx.z ? LG : LU;
  const int tid = threadIdx.x, lane = tid&63, wave = tid>>6;
  const int wm=(wave>>1)*64, wn=(wave&1)*64, fr=lane&15, quad=lane>>4;
  f32x4 l0[4][4], l1[4][4];
  #pragma unroll
  for(int i=0;i<4;i++)
    #pragma unroll
    for(int j=0;j<4;j++){ l0[i][j]=(f32x4){0.f,0.f,0.f,0.f}; l1[i][j]=l0[i][j]; }
  const Stage sB  = mk_stage(Bcat + (long)h0*128, 128, Bt, tid);
  const Stage sR0 = mk_stage(Rsel + (long)t0*128, 128, At, tid);
  const Stage sR1 = mk_stage(Rsel + ((long)TOKENS + t0)*128, 128, Gt, tid);
  for(int k0=0; k0<128; k0+=32){
    do_stage(sB, k0); do_stage(sR0, k0); do_stage(sR1, k0);
    __syncthreads();
    f16x8 a0[4], a1[4];
    #pragma unroll
    for(int i=0;i<4;i++){ a0[i] = fragh(At, wm + i*16 + fr, quad); a1[i] = fragh(Gt, wm + i*16 + fr, quad); }
    #pragma unroll
    for(int j=0;j<4;j++){
      const f16x8 bf = fragh(Bt, wn + j*16 + fr, quad);
      #pragma unroll
      for(int i=0;i<4;i++){
        l0[i][j] = __builtin_amdgcn_mfma_f32_16x16x32_f16(a0[i], bf, l0[i][j], 0,0,0);
        l1[i][j] = __builtin_amdgcn_mfma_f32_16x16x32_f16(a1[i], bf, l1[i][j], 0,0,0);
      }
    }
    __syncthreads();
  }
  #pragma unroll
  for(int i=0;i<4;i++)
    #pragma unroll
    for(int j=0;j<4;j++){
      const int rbase = wm + i*16 + quad*4, col = wn + j*16 + fr;
      #pragma unroll
      for(int reg=0;reg<4;reg++){
        LoopStore:;
        Lout[((long)(t0+rbase+reg))*DHID + h0 + col]          = __float2half(l0[i][j][reg]);
        Lout[((long)TOKENS + t0+rbase+reg)*DHID + h0 + col]   = __float2half(l1[i][j][reg]);
      }
    }
}

// ---------------- K4: base up/gate GEMM + load-LoRA epilogue -> ch0, ch1, chsum (bf16) ----------------
__global__ __launch_bounds__(256,2) void k_main(
    const short* __restrict__ xb, const short* __restrict__ wub, const short* __restrict__ wgb,
    const __half* __restrict__ LU, const __half* __restrict__ LG,
    const float* __restrict__ cw, unsigned short* __restrict__ ch, unsigned short* __restrict__ chsum){
  __shared__ __align__(16) short At[4096];
  __shared__ __align__(16) short Ut[4096];
  __shared__ __align__(16) short Gt[4096];
  __shared__ float cwv[128][2];
  const int h0 = blockIdx.x*128, t0 = blockIdx.y*128;
  const int tid = threadIdx.x, lane = tid&63, wave = tid>>6;
  const int wm=(wave>>1)*64, wn=(wave&1)*64, fr=lane&15, quad=lane>>4;
  if(tid < 256){ const int tl = tid>>1, k = tid&1; cwv[tl][k] = cw[(t0+tl)*2 + k]; }
  f32x4 au[4][4], ag[4][4];
  #pragma unroll
  for(int i=0;i<4;i++)
    #pragma unroll
    for(int j=0;j<4;j++){ au[i][j]=(f32x4){0.f,0.f,0.f,0.f}; ag[i][j]=au[i][j]; }
  const Stage sA = mk_stage(xb + (long)t0*DMODEL, DMODEL, At, tid);
  const Stage sU = mk_stage(wub + (long)h0*DMODEL, DMODEL, Ut, tid);
  const Stage sG = mk_stage(wgb + (long)h0*DMODEL, DMODEL, Gt, tid);
  for(int k0=0; k0<DMODEL; k0+=32){
    do_stage(sA, k0); do_stage(sU, k0); do_stage(sG, k0);
    __syncthreads();
    s16x8 af[4];
    #pragma unroll
    for(int i=0;i<4;i++) af[i] = fragb(At, wm + i*16 + fr, quad);
    #pragma unroll
    for(int j=0;j<4;j++){
      const s16x8 bu = fragb(Ut, wn + j*16 + fr, quad);
      const s16x8 bg = fragb(Gt, wn + j*16 + fr, quad);
      #pragma unroll
      for(int i=0;i<4;i++){
        au[i][j] = __builtin_amdgcn_mfma_f32_16x16x32_bf16(af[i], bu, au[i][j], 0,0,0);
        ag[i][j] = __builtin_amdgcn_mfma_f32_16x16x32_bf16(af[i], bg, ag[i][j], 0,0,0);
      }
    }
    __syncthreads();
  }
  // ---- epilogue: load precomputed LoRA deltas, silu*gate, scale, write 3 streams ----
  #pragma unroll
  for(int i=0;i<4;i++){
    #pragma unroll
    for(int reg=0;reg<4;reg++){
      const int tl = wm + i*16 + quad*4 + reg;
      const float c0 = cwv[tl][0], c1 = cwv[tl][1];
      const long row0 = (long)(t0+tl)*DHID + h0;
      const long row1 = ((long)TOKENS + t0+tl)*DHID + h0;
      const __half* pu0 = LU + row0; const __half* pu1 = LU + row1;
      const __half* pg0 = LG + row0; const __half* pg1 = LG + row1;
      unsigned short* r0 = ch + row0;
      unsigned short* r1 = ch + row1;
      unsigned short* rs = chsum + row0;
      #pragma unroll
      for(int j=0;j<4;j++){
        const int hl = wn + j*16 + fr;
        const float u0 = au[i][j][reg] + __half2float(pu0[hl]);
        const float g0 = ag[i][j][reg] + __half2float(pg0[hl]);
        const float h0v = (u0 / (1.f + __expf(-u0))) * g0;
        const float u1 = au[i][j][reg] + __half2float(pu1[hl]);
        const float g1 = ag[i][j][reg] + __half2float(pg1[hl]);
        const float h1v = (u1 / (1.f + __expf(-u1))) * g1;
        const float v0 = c0*h0v, v1 = c1*h1v;
        r0[hl] = (unsigned short)f2bf(v0);
        r1[hl] = (unsigned short)f2bf(v1);
        rs[hl] = (unsigned short)f2bf(v0+v1);
      }
    }
  }
}

// ---------------- K5: RD[t][k][c] = ch_k @ daA^T (ksplit=16, atomics) ----------------
__global__ __launch_bounds__(256,4) void k_rd(
    const unsigned short* __restrict__ ch, const short* __restrict__ daA,
    float* __restrict__ RD){
  __shared__ __align__(16) short At[4096];
  __shared__ __align__(16) short Bt[4096];
  const int slot = blockIdx.x>>4, ks = blockIdx.x&15;
  const int t0 = blockIdx.y*128;
  const int tid = threadIdx.x, lane = tid&63, wave = tid>>6;
  const int wm=(wave>>1)*64, wn=(wave&1)*64, fr=lane&15, quad=lane>>4;
  f32x4 acc[4][4];
  #pragma unroll
  for(int i=0;i<4;i++)
    #pragma unroll
    for(int j=0;j<4;j++) acc[i][j]=(f32x4){0.f,0.f,0.f,0.f};
  const Stage sA = mk_stage((const short*)ch + ((long)slot*TOKENS + t0)*DHID, DHID, At, tid);
  const Stage sB = mk_stage(daA, DHID, Bt, tid);
  const int kbeg = ks*352;
  for(int kk=0; kk<352; kk+=32){
    do_stage(sA, kbeg+kk); do_stage(sB, kbeg+kk);
    __syncthreads();
    s16x8 af[4];
    #pragma unroll
    for(int i=0;i<4;i++) af[i] = fragb(At, wm + i*16 + fr, quad);
    #pragma unroll
    for(int j=0;j<4;j++){
      const s16x8 bf = fragb(Bt, wn + j*16 + fr, quad);
      #pragma unroll
      for(int i=0;i<4;i++)
        acc[i][j] = __builtin_amdgcn_mfma_f32_16x16x32_bf16(af[i], bf, acc[i][j], 0,0,0);
    }
    __syncthreads();
  }
  #pragma unroll
  for(int i=0;i<4;i++)
    #pragma unroll
    for(int j=0;j<4;j++){
      const int rbase = wm + i*16 + quad*4, col = wn + j*16 + fr;
      #pragma unroll
      for(int reg=0;reg<4;reg++)
        atomicAdd(&RD[((long)(t0+rbase+reg)*2 + slot)*128 + col], acc[i][j][reg]);
    }
}

// ---------------- K5b: RDhat[t][c] (f16) = alpha * RD at selected expert blocks ----------------
__global__ void k_scatter(const float* __restrict__ RD, const int* __restrict__ sel,
                          __half* __restrict__ RDhat){
  const int idx = blockIdx.x*256 + threadIdx.x;   // over T*128
  const int t = idx>>7, c = idx&127, e = c>>4;
  const int s0 = sel[t*2], s1 = sel[t*2+1];
  float v = 0.f;
  if(e == s0) v = LALPHA * RD[((long)t*2+0)*128 + c];
  else if(e == s1) v = LALPHA * RD[((long)t*2+1)*128 + c];
  RDhat[idx] = __float2half(v);
}

// ---------------- K6: out += chsum @ wdb^T (split-K=2) + RDhat @ wdbcat^T ----------------
__global__ __launch_bounds__(256,4) void k_down(
    const unsigned short* __restrict__ chsum, const short* __restrict__ wdb,
    const short* __restrict__ RDhat, const short* __restrict__ wdbcat,
    float* __restrict__ out){
  __shared__ __align__(16) short At[4096];
  __shared__ __align__(16) short Bt[4096];
  const int d0 = blockIdx.x*128, t0 = blockIdx.y*128, ks = blockIdx.z;
  const int tid = threadIdx.x, lane = tid&63, wave = tid>>6;
  const int wm=(wave>>1)*64, wn=(wave&1)*64, fr=lane&15, quad=lane>>4;
  f32x4 acc[4][4];
  #pragma unroll
  for(int i=0;i<4;i++)
    #pragma unroll
    for(int j=0;j<4;j++) acc[i][j]=(f32x4){0.f,0.f,0.f,0.f};
  const Stage sA = mk_stage((const short*)chsum + (long)t0*DHID, DHID, At, tid);
  const Stage sB = mk_stage(wdb + (long)d0*DHID, DHID, Bt, tid);
  const int kbeg = ks*2816;
  for(int kk=0; kk<2816; kk+=32){
    do_stage(sA, kbeg+kk); do_stage(sB, kbeg+kk);
    __syncthreads();
    s16x8 af[4];
    #pragma unroll
    for(int i=0;i<4;i++) af[i] = fragb(At, wm + i*16 + fr, quad);
    #pragma unroll
    for(int j=0;j<4;j++){
      const s16x8 bf = fragb(Bt, wn + j*16 + fr, quad);
      #pragma unroll
      for(int i=0;i<4;i++)
        acc[i][j] = __builtin_amdgcn_mfma_f32_16x16x32_bf16(af[i], bf, acc[i][j], 0,0,0);
    }
    __syncthreads();
  }
  if(ks == 0){
    // LoRA-down phase: K=128 over RDhat (f16) @ wdbcat (f16)
    const Stage sAh = mk_stage(RDhat + (long)t0*128, 128, At, tid);
    const Stage sBh = mk_stage(wdbcat + (long)d0*128, 128, Bt, tid);
    for(int k0=0; k0<128; k0+=32){
      do_stage(sAh, k0); do_stage(sBh, k0);
      __syncthreads();
      f16x8 af[4];
      #pragma unroll
      for(int i=0;i<4;i++) af[i] = fragh(At, wm + i*16 + fr, quad);
      #pragma unroll
      for(int j=0;j<4;j++){
        const f16x8 bf = fragh(Bt, wn + j*16 + fr, quad);
        #pragma unroll
        for(int i=0;i<4;i++)
          acc[i][j] = __builtin_amdgcn_mfma_f32_16x16x32_f16(af[i], bf, acc[i][j], 0,0,0);
      }
      __syncthreads();
    }
  }
  #pragma unroll
  for(int i=0;i<4;i++)
    #pragma unroll
    for(int j=0;j<4;j++){
      const int rbase = wm + i*16 + quad*4, col = wn + j*16 + fr;
      #pragma unroll
      for(int reg=0;reg<4;reg++)
        atomicAdd(&out[(long)(t0+rbase+reg)*DMODEL + d0 + col], acc[i][j][reg]);
    }
}

extern "C" void kernel_launch(void* const* d_in, const int* in_sizes, int n_in,
                              void* d_out, int out_size, void* d_ws, size_t ws_size,
                              hipStream_t stream){
  (void)in_sizes; (void)n_in; (void)out_size; (void)ws_size;
  const float* x      = (const float*)d_in[0];
  const float* gate_w = (const float*)d_in[1];
  const float* w_up   = (const float*)d_in[2];
  const float* w_gate = (const float*)d_in[3];
  const float* w_down = (const float*)d_in[4];
  const float* up_A   = (const float*)d_in[5];
  const float* up_B   = (const float*)d_in[6];
  const float* gate_A = (const float*)d_in[7];
  const float* gate_B = (const float*)d_in[8];
  const float* down_A = (const float*)d_in[9];
  const float* down_B = (const float*)d_in[10];
  float* out = (float*)d_out;

  char* ws = (char*)d_ws;
  size_t off = 0;
  auto alloc = [&](size_t bytes){ void* p = ws + off; off += (bytes + 255) & ~(size_t)255; return p; };
  short* xb       = (short*)alloc((size_t)TOKENS*DMODEL*2);
  short* wub      = (short*)alloc((size_t)DHID*DMODEL*2);
  short* wgb      = (short*)alloc((size_t)DHID*DMODEL*2);
  short* wdb      = (short*)alloc((size_t)DMODEL*DHID*2);
  short* daA      = (short*)alloc((size_t)128*DHID*2);
  short* acat     = (short*)alloc((size_t)256*DMODEL*2);
  short* upBcat   = (short*)alloc((size_t)DHID*128*2);
  short* gateBcat = (short*)alloc((size_t)DHID*128*2);
  short* wdbcat   = (short*)alloc((size_t)DMODEL*128*2);
  unsigned short* ch    = (unsigned short*)alloc((size_t)2*TOKENS*DHID*2);
  unsigned short* chsum = (unsigned short*)alloc((size_t)TOKENS*DHID*2);
  __half* LU    = (__half*)alloc((size_t)2*TOKENS*DHID*2);
  __half* LG    = (__half*)alloc((size_t)2*TOKENS*DHID*2);
  float* Rall   = (float*)alloc((size_t)TOKENS*256*4);
  short* RselU  = (short*)alloc((size_t)2*TOKENS*128*2);
  short* RselG  = (short*)alloc((size_t)2*TOKENS*128*2);
  float* RD     = (float*)alloc((size_t)TOKENS*2*128*4);
  __half* RDhat = (__half*)alloc((size_t)TOKENS*128*2);
  int*   sel    = (int*)alloc((size_t)TOKENS*2*4);
  float* topv   = (float*)alloc((size_t)TOKENS*2*4);
  float* cw     = (float*)alloc((size_t)TOKENS*2*4);

  (void)hipMemsetAsync(RD, 0, (size_t)TOKENS*2*128*4, stream);
  (void)hipMemsetAsync(out, 0, (size_t)TOKENS*DMODEL*4, stream);
  k_cast<<<40768, 256, 0, stream>>>(x, w_up, w_gate, w_down, up_A, gate_A, down_A,
                                    up_B, gate_B, down_B,
                                    xb, wub, wgb, wdb, daA, acat, upBcat, gateBcat, wdbcat);
  k_router<<<512, 256, 0, stream>>>(x, gate_w, sel, topv);
  k_softmax<<<4, 256, 0, stream>>>(topv, cw);
  k_rank<<<dim3(2,16), 256, 0, stream>>>(xb, acat, Rall);
  k_rsel<<<2048, 256, 0, stream>>>(Rall, sel, RselU, RselG);
  k_lora<<<dim3(44,16,2), 256, 0, stream>>>(RselU, RselG, upBcat, gateBcat, LU, LG);
  k_main<<<dim3(44,16), 256, 0, stream>>>(xb, wub, wgb, LU, LG, cw, ch, chsum);
  k_rd<<<dim3(32,16), 256, 0, stream>>>(ch, daA, RD);
  k_scatter<<<1024, 256, 0, stream>>>(RD, sel, RDhat);
  k_down<<<dim3(16,16,2), 256, 0, stream>>>(chsum, wdb, (const short*)RDhat, wdbcat, out);
}